// Round 8
// baseline (121.106 us; speedup 1.0000x reference)
//
#include <hip/hip_runtime.h>

#define LOG64f 4.1588830833596715f
#define LOG32f 3.4657359027997265f
#define LOG16f 2.7725887222397810f

// Persistent grid-stride waves, 2-deep register double-buffer.
// One group = 16 consecutive fragments, one wave per group-stream.
// Steady state: issue group (g+stride)'s bc loads + index chain, then compute
// group g -- so every compute/shuffle tail runs with a full 1KB-coalesced
// load burst in flight. Geometry identical to round 4 (every big-array load
// is a contiguous 1KB wave transaction, each byte touched exactly once).

struct Frag {
    int4 c00, c01, c02, c03, c10, c11, c20;
    float dva, dvb, dvc;
    int g0, g1, g2, b0, b1, b2;
};

__device__ __forceinline__ void expsum4(const int4 c, const float4 w, const float dv,
                                        const int b, const int sub, float& s, float& ub)
{
    const float u0 = (c.x > 1 ? dv : 0.f) + w.x;
    const float u1 = (c.y > 1 ? dv : 0.f) + w.y;
    const float u2 = (c.z > 1 ? dv : 0.f) + w.z;
    const float u3 = (c.w > 1 ? dv : 0.f) + w.w;
    s  = (__expf(u0) + __expf(u1)) + (__expf(u2) + __expf(u3));
    ub = 0.f;
    if (sub == (b >> 2)) {
        const int r = b & 3;
        ub = r == 0 ? u0 : r == 1 ? u1 : r == 2 ? u2 : u3;
    }
}

__device__ __forceinline__ void load_group(
    Frag& F, const int base, const int NM1, const int lane,
    const int* __restrict__ bc0, const int* __restrict__ bc1, const int* __restrict__ bc2,
    const int* __restrict__ gix, const int* __restrict__ bix,
    const int* __restrict__ labels, const int* __restrict__ lci,
    const float* __restrict__ d0, const float* __restrict__ d1, const float* __restrict__ d2)
{
    const int s16 = lane >> 4, s8 = lane >> 3, s4 = lane >> 2;
    const int sub0 = lane & 15, sub1 = lane & 7, sub2 = lane & 3;
    const int fl = lane & 15;

    // big streaming loads first (contiguous 1KB per wave instruction)
    const int n00 = min(base +      s16, NM1), n01 = min(base +  4 + s16, NM1),
              n02 = min(base +  8 + s16, NM1), n03 = min(base + 12 + s16, NM1);
    const int n10 = min(base +       s8, NM1), n11 = min(base +  8 +  s8, NM1);
    const int n20 = min(base +       s4, NM1);

    F.c00 = ((const int4*)(bc0 + (size_t)n00 * 64))[sub0];
    F.c01 = ((const int4*)(bc0 + (size_t)n01 * 64))[sub0];
    F.c02 = ((const int4*)(bc0 + (size_t)n02 * 64))[sub0];
    F.c03 = ((const int4*)(bc0 + (size_t)n03 * 64))[sub0];
    F.c10 = ((const int4*)(bc1 + (size_t)n10 * 32))[sub1];
    F.c11 = ((const int4*)(bc1 + (size_t)n11 * 32))[sub1];
    F.c20 = ((const int4*)(bc2 + (size_t)n20 * 16))[sub2];

    // per-fragment scalar chain (owner lane fl <-> fragment base+fl)
    const int nf = min(base + fl, NM1);
    const int cell = lci[nf];
    F.g0 = gix[3 * nf + 0]; F.g1 = gix[3 * nf + 1]; F.g2 = gix[3 * nf + 2];
    F.b0 = bix[3 * nf + 0]; F.b1 = bix[3 * nf + 1]; F.b2 = bix[3 * nf + 2];
    const int lab = labels[cell];
    F.dva = d0[lab]; F.dvb = d1[lab]; F.dvc = d2[lab];
}

__device__ __forceinline__ void compute_store(
    const Frag& F, const int lane, const int base, const int N,
    const float* __restrict__ bw0, const float* __restrict__ bw1,
    const float* __restrict__ bw2, float* __restrict__ out)
{
    const int fl = lane & 15;
    const int s16 = lane >> 4, s8 = lane >> 3, s4 = lane >> 2;
    const int f00 = s16, f01 = 4 + s16, f02 = 8 + s16, f03 = 12 + s16;
    const int f10 = s8,  f11 = 8 + s8;
    const int f20 = s4;
    const int sub0 = lane & 15, sub1 = lane & 7, sub2 = lane & 3;

    // broadcasts (segment gets its fragment's scalars)
    const float dv00 = __shfl(F.dva, f00), dv01 = __shfl(F.dva, f01),
                dv02 = __shfl(F.dva, f02), dv03 = __shfl(F.dva, f03);
    const int   g00  = __shfl(F.g0, f00), g01 = __shfl(F.g0, f01),
                g02  = __shfl(F.g0, f02), g03 = __shfl(F.g0, f03);
    const int   b00  = __shfl(F.b0, f00), b01 = __shfl(F.b0, f01),
                b02  = __shfl(F.b0, f02), b03 = __shfl(F.b0, f03);
    const float dv10 = __shfl(F.dvb, f10), dv11 = __shfl(F.dvb, f11);
    const int   g10  = __shfl(F.g1, f10), g11 = __shfl(F.g1, f11);
    const int   b10  = __shfl(F.b1, f10), b11 = __shfl(F.b1, f11);
    const float dv20 = __shfl(F.dvc, f20);
    const int   g20  = __shfl(F.g2, f20);
    const int   b20  = __shfl(F.b2, f20);

    // baseline row loads (contiguous 1KB/wave, L2-resident tables)
    const float4 w00 = ((const float4*)(bw0 + (size_t)g00 * 64))[sub0];
    const float4 w01 = ((const float4*)(bw0 + (size_t)g01 * 64))[sub0];
    const float4 w02 = ((const float4*)(bw0 + (size_t)g02 * 64))[sub0];
    const float4 w03 = ((const float4*)(bw0 + (size_t)g03 * 64))[sub0];
    const float4 w10 = ((const float4*)(bw1 + (size_t)g10 * 32))[sub1];
    const float4 w11 = ((const float4*)(bw1 + (size_t)g11 * 32))[sub1];
    const float4 w20 = ((const float4*)(bw2 + (size_t)g20 * 16))[sub2];

    // exp-sums + holder u[b]
    float s00, u00, s01, u01, s02, u02, s03, u03;
    expsum4(F.c00, w00, dv00, b00, sub0, s00, u00);
    expsum4(F.c01, w01, dv01, b01, sub0, s01, u01);
    expsum4(F.c02, w02, dv02, b02, sub0, s02, u02);
    expsum4(F.c03, w03, dv03, b03, sub0, s03, u03);
    #pragma unroll
    for (int off = 1; off <= 8; off <<= 1) {
        s00 += __shfl_xor(s00, off); s01 += __shfl_xor(s01, off);
        s02 += __shfl_xor(s02, off); s03 += __shfl_xor(s03, off);
    }
    float s10, u10, s11, u11;
    expsum4(F.c10, w10, dv10, b10, sub1, s10, u10);
    expsum4(F.c11, w11, dv11, b11, sub1, s11, u11);
    #pragma unroll
    for (int off = 1; off <= 4; off <<= 1) {
        s10 += __shfl_xor(s10, off); s11 += __shfl_xor(s11, off);
    }
    float s20, u20;
    expsum4(F.c20, w20, dv20, b20, sub2, s20, u20);
    s20 += __shfl_xor(s20, 1); s20 += __shfl_xor(s20, 2);

    // gather S (segment sums) and U (direct from holder lane)
    const int  src0 = (fl & 3) << 4;
    const float m00 = __shfl(s00, src0), m01 = __shfl(s01, src0),
                m02 = __shfl(s02, src0), m03 = __shfl(s03, src0);
    const int j0 = fl >> 2;
    const float S0 = j0 == 0 ? m00 : j0 == 1 ? m01 : j0 == 2 ? m02 : m03;
    const int  h0 = src0 + (F.b0 >> 2);
    const float x00 = __shfl(u00, h0), x01 = __shfl(u01, h0),
                x02 = __shfl(u02, h0), x03 = __shfl(u03, h0);
    const float U0 = j0 == 0 ? x00 : j0 == 1 ? x01 : j0 == 2 ? x02 : x03;

    const int  src1 = (fl & 7) << 3;
    const float m10 = __shfl(s10, src1), m11 = __shfl(s11, src1);
    const float S1 = (fl >> 3) == 0 ? m10 : m11;
    const int  h1 = src1 + (F.b1 >> 2);
    const float x10 = __shfl(u10, h1), x11 = __shfl(u11, h1);
    const float U1 = (fl >> 3) == 0 ? x10 : x11;

    const float S2 = __shfl(s20, fl << 2);
    const float U2 = __shfl(u20, (fl << 2) + (F.b2 >> 2));

    const float acc = (U0 - __logf(S0) + LOG64f) +
                      (U1 - __logf(S1) + LOG32f) +
                      (U2 - __logf(S2) + LOG16f);

    if (lane < 16) {
        const int n = base + lane;
        if (n < N) out[n] = acc;
    }
}

__global__ __launch_bounds__(256) void frag_pos_dist_kernel(
    const int* __restrict__ bc0, const int* __restrict__ bc1, const int* __restrict__ bc2,
    const int* __restrict__ gix, const int* __restrict__ bix,
    const int* __restrict__ labels, const int* __restrict__ lci,
    const float* __restrict__ bw0, const float* __restrict__ d0,
    const float* __restrict__ bw1, const float* __restrict__ d1,
    const float* __restrict__ bw2, const float* __restrict__ d2,
    float* __restrict__ out, int N)
{
    const int lane   = threadIdx.x & 63;
    const int nWaves = gridDim.x * (blockDim.x >> 6);
    const int wid    = blockIdx.x * (blockDim.x >> 6) + (threadIdx.x >> 6);
    const int nGroups = (N + 15) >> 4;
    const int NM1 = N - 1;

    int g = wid;
    if (g >= nGroups) return;

    Frag A, B;
    load_group(A, g * 16, NM1, lane, bc0, bc1, bc2, gix, bix, labels, lci, d0, d1, d2);
    int gn = g + nWaves;
    bool moreB = gn < nGroups;
    if (moreB)
        load_group(B, gn * 16, NM1, lane, bc0, bc1, bc2, gix, bix, labels, lci, d0, d1, d2);

    for (;;) {
        // compute A (B's loads in flight)
        compute_store(A, lane, g * 16, N, bw0, bw1, bw2, out);
        if (!moreB) return;
        g = gn; gn = g + nWaves;
        const bool moreA = gn < nGroups;
        if (moreA)
            load_group(A, gn * 16, NM1, lane, bc0, bc1, bc2, gix, bix, labels, lci, d0, d1, d2);
        // compute B (A's new loads in flight)
        compute_store(B, lane, g * 16, N, bw0, bw1, bw2, out);
        if (!moreA) return;
        g = gn; gn = g + nWaves;
        moreB = gn < nGroups;
        if (moreB)
            load_group(B, gn * 16, NM1, lane, bc0, bc1, bc2, gix, bix, labels, lci, d0, d1, d2);
    }
}

extern "C" void kernel_launch(void* const* d_in, const int* in_sizes, int n_in,
                              void* d_out, int out_size, void* d_ws, size_t ws_size,
                              hipStream_t stream) {
    const int* bc0    = (const int*)d_in[0];
    const int* bc1    = (const int*)d_in[1];
    const int* bc2    = (const int*)d_in[2];
    const int* gix    = (const int*)d_in[3];
    const int* bixp   = (const int*)d_in[4];
    const int* labels = (const int*)d_in[5];
    const int* lci    = (const int*)d_in[6];
    const float* bw0  = (const float*)d_in[7];
    const float* dv0  = (const float*)d_in[8];
    const float* bw1  = (const float*)d_in[9];
    const float* dv1  = (const float*)d_in[10];
    const float* bw2  = (const float*)d_in[11];
    const float* dv2  = (const float*)d_in[12];
    float* out = (float*)d_out;

    const int N = in_sizes[6];           // local_cell_ix has N elements
    const int nGroups = (N + 15) / 16;
    const int wavesPerBlock = 4;         // 256 threads
    const int maxBlocks = 2048;          // persistent-ish; ~8 groups per wave
    int blocks = (nGroups + wavesPerBlock - 1) / wavesPerBlock;
    if (blocks > maxBlocks) blocks = maxBlocks;

    frag_pos_dist_kernel<<<blocks, 256, 0, stream>>>(
        bc0, bc1, bc2, gix, bixp, labels, lci,
        bw0, dv0, bw1, dv1, bw2, dv2, out, N);
}